// Round 1
// baseline (67.022 us; speedup 1.0000x reference)
//
#include <hip/hip_runtime.h>
#include <hip/hip_bf16.h>

typedef short short8 __attribute__((ext_vector_type(8)));
typedef float f32x4 __attribute__((ext_vector_type(4)));

#define INV_SQRT2F 0.70710678118654752440f

__device__ __forceinline__ unsigned short f2bf(float f) {
  union { float f; unsigned u; } v; v.f = f;
  unsigned u = v.u;
  unsigned r = (u + 0x7FFFu + ((u >> 16) & 1u)) >> 16;  // RNE
  return (unsigned short)r;
}

// ---------------------------------------------------------------------------
// Precompute: W'[e,:] = inverse Haar transform of W[e,:]  (since out = (W H) x),
// packed as bf16 in MFMA B-fragment layout:
//   flat bf16 index = ((nblk*8 + kk)*64 + lane)*8 + j
//   where e = nblk*16 + (lane&15), k = kk*32 + (lane>>4)*8 + j
// One wave per row e; 4 waves per block.
// ---------------------------------------------------------------------------
__global__ void haar_pack(const float* __restrict__ W, unsigned short* __restrict__ Wp) {
  __shared__ float cbuf[4][256];
  __shared__ float buf0[4][256];
  __shared__ float buf1[4][256];
  const int tid = threadIdx.x;
  const int w = tid >> 6, l = tid & 63;
  const int e = blockIdx.x * 4 + w;
  const float* row = W + e * 256;
  for (int k = l; k < 256; k += 64) cbuf[w][k] = row[k];
  __syncthreads();
  if (l == 0) buf0[w][0] = cbuf[w][0];   // a = [cA_8]
  __syncthreads();
  float* A = buf0[w];
  float* Bv = buf1[w];
  int len = 1;
  // coeff layout: [cA_8(1), cD_8(1), cD_7(2), ..., cD_1(128)]; offset(cD_lev)=len
  for (int s = 0; s < 8; ++s) {
    for (int k = l; k < len; k += 64) {
      float av = A[k], dv = cbuf[w][len + k];
      Bv[2 * k]     = (av + dv) * INV_SQRT2F;   // even
      Bv[2 * k + 1] = (av - dv) * INV_SQRT2F;   // odd
    }
    __syncthreads();
    float* t = A; A = Bv; Bv = t;
    len <<= 1;
  }
  // A now holds W'[e, 0..255]; pack to fragment layout
  const int nblk = e >> 4, lr = e & 15;
  for (int k = l; k < 256; k += 64) {
    int kk = k >> 5, win = k & 31, lhi = win >> 3, j = win & 7;
    int lane = lhi * 16 + lr;
    Wp[(((nblk * 8 + kk) * 64 + lane) << 3) + j] = f2bf(A[k]);
  }
}

// ---------------------------------------------------------------------------
// GEMM: out[m, e] = sum_k x[m,k]*W'[e,k] + b[e]
// M = 131072, N = 256 (full width per block), K = 256 (fully staged).
// Block: 256 thr = 4 waves (2M x 2N); wave tile 64x128; BM=128.
// A tile in LDS as bf16, XOR-swizzled: byte = row*512 + ((col*2) ^ ((row&7)<<4))
// ---------------------------------------------------------------------------
__global__ __launch_bounds__(256, 2) void wemb_gemm(
    const float* __restrict__ x, const unsigned short* __restrict__ Wp,
    const float* __restrict__ bias, float* __restrict__ out, int Mrows) {
  __shared__ char lds[65536];
  const int tid = threadIdx.x;
  const long blockRow = (long)blockIdx.x * 128;
  const float4* xblk = (const float4*)(x + blockRow * 256);

  // ---- stage A: 128 rows x 256 cols fp32 -> bf16 LDS (tile is contiguous) ----
#pragma unroll
  for (int i = 0; i < 32; ++i) {
    int f = i * 256 + tid;          // float4 index in tile
    float4 v = xblk[f];
    int row = f >> 6;               // (f*4) >> 8
    int colb = (f & 63) * 8;        // byte offset of col within row (col*2)
    ushort4 p;
    p.x = f2bf(v.x); p.y = f2bf(v.y); p.z = f2bf(v.z); p.w = f2bf(v.w);
    int byte = row * 512 + (colb ^ ((row & 7) << 4));
    *(ushort4*)(lds + byte) = p;    // ds_write_b64
  }
  __syncthreads();

  const int w = tid >> 6, lane = tid & 63;
  const int wm = w >> 1, wn = w & 1;
  const int lr = lane & 15, lhi = lane >> 4;

  f32x4 acc[4][8];
#pragma unroll
  for (int m = 0; m < 4; ++m)
#pragma unroll
    for (int n = 0; n < 8; ++n) acc[m][n] = (f32x4){0.f, 0.f, 0.f, 0.f};

  const short8* bp = (const short8*)Wp;
#pragma unroll
  for (int kk = 0; kk < 8; ++kk) {
    short8 a[4];
#pragma unroll
    for (int m = 0; m < 4; ++m) {
      int row = wm * 64 + m * 16 + lr;
      int colb = (kk * 32 + lhi * 8) * 2;
      int byte = row * 512 + (colb ^ ((row & 7) << 4));
      a[m] = *(const short8*)(lds + byte);   // ds_read_b128, conflict-free
    }
#pragma unroll
    for (int n = 0; n < 8; ++n) {
      short8 b = bp[((wn * 8 + n) * 8 + kk) * 64 + lane];  // coalesced, L2-hot
#pragma unroll
      for (int m = 0; m < 4; ++m)
        acc[m][n] = __builtin_amdgcn_mfma_f32_16x16x32_bf16(a[m], b, acc[m][n], 0, 0, 0);
    }
  }

  // ---- epilogue: bias + store (C/D: col=lane&15 -> e, row=(lane>>4)*4+r) ----
#pragma unroll
  for (int n = 0; n < 8; ++n) {
    int e = wn * 128 + n * 16 + lr;
    float bv = bias[e];
#pragma unroll
    for (int m = 0; m < 4; ++m) {
      float* o = out + (blockRow + wm * 64 + m * 16 + lhi * 4) * 256 + e;
#pragma unroll
      for (int r = 0; r < 4; ++r) o[r * 256] = acc[m][n][r] + bv;
    }
  }
  (void)Mrows;
}

extern "C" void kernel_launch(void* const* d_in, const int* in_sizes, int n_in,
                              void* d_out, int out_size, void* d_ws, size_t ws_size,
                              hipStream_t stream) {
  const float* x = (const float*)d_in[0];     // (16, 8192, 256) fp32
  const float* W = (const float*)d_in[1];     // (256, 256) fp32
  const float* b = (const float*)d_in[2];     // (256,) fp32
  float* out = (float*)d_out;                 // (16, 8192, 256) fp32
  unsigned short* Wp = (unsigned short*)d_ws; // 256*256 bf16 = 128 KB

  haar_pack<<<64, 256, 0, stream>>>(W, Wp);

  const int Mrows = out_size / 256;           // 131072
  const int grid = Mrows / 128;               // 1024
  wemb_gemm<<<grid, 256, 0, stream>>>(x, Wp, b, out, Mrows);
}